// Round 1
// baseline (671.360 us; speedup 1.0000x reference)
//
#include <hip/hip_runtime.h>

#define ALPHA_MARGIN 1.0f

// Grid-stride persistent kernel: 2048 blocks x 256 threads = 8192 waves
// (exactly 32 waves/CU x 256 CUs). Each wave processes TWO pairs per step:
//   lanes  0..31 (half h=0) handle pair p0,   lanes 32..63 (h=1) handle p0+1.
// Within a half, lane i loads the i-th float4 of e_a and of e_b directly
// (two coalesced 512B segments per load instruction), so no cross-half
// exchange shuffles are needed; only a 5-step xor-reduce within the
// 32-lane half (masks <=16 never cross the half boundary).
__global__ __launch_bounds__(256) void closs_kernel(
        const float4* __restrict__ X4,
        const int*    __restrict__ y,
        float*        __restrict__ out,
        int n_pairs) {
    const int lane = threadIdx.x & 63;
    const int h    = lane >> 5;         // which pair of the step this half owns
    const int i    = lane & 31;         // float4 index within the 128-float half
    const int wave = (int)((blockIdx.x * blockDim.x + threadIdx.x) >> 6);
    const int nwav = (int)((gridDim.x * blockDim.x) >> 6);

    for (int p0 = wave * 2; p0 < n_pairs; p0 += nwav * 2) {
        const int p = p0 + h;
        if (p < n_pairs) {              // only the tail step can diverge here
            const size_t base = (size_t)p * 64;
            float4 va = X4[base + i];        // e_a chunk: floats [i*4 .. i*4+3]
            float4 vb = X4[base + 32 + i];   // e_b chunk: floats [128+i*4 ..]
            float dx = va.x - vb.x;
            float dy = va.y - vb.y;
            float dz = va.z - vb.z;
            float dw = va.w - vb.w;
            float s = dx * dx + dy * dy + dz * dz + dw * dw;

            #pragma unroll
            for (int m = 16; m >= 1; m >>= 1)
                s += __shfl_xor(s, m);

            if (i == 0) {
                int adj = y[p];
                float loss;
                if (adj == 1)      loss = s;
                else if (adj == 0) loss = fmaxf(ALPHA_MARGIN - s, 0.0f);
                else               loss = 0.0f;
                out[p] = loss;
            }
        }
    }
}

extern "C" void kernel_launch(void* const* d_in, const int* in_sizes, int n_in,
                              void* d_out, int out_size, void* d_ws, size_t ws_size,
                              hipStream_t stream) {
    const float* X = (const float*)d_in[0];
    const int*   y = (const int*)d_in[1];
    float* out = (float*)d_out;

    int n_pairs = in_sizes[1];           // B * N * N = 524288

    // 8 pairs per block per sweep (4 waves x 2 pairs); cap grid at 2048 blocks
    // (32 waves/CU x 256 CU) and grid-stride — avoids the 131k tiny-block
    // dispatch-rate bottleneck.
    int blocks = (n_pairs + 7) / 8;
    if (blocks > 2048) blocks = 2048;

    closs_kernel<<<blocks, 256, 0, stream>>>((const float4*)X, y, out, n_pairs);
}